// Round 4
// baseline (772.579 us; speedup 1.0000x reference)
//
#include <hip/hip_runtime.h>
#include <stdint.h>

typedef __attribute__((ext_vector_type(8))) short short8;
typedef __attribute__((ext_vector_type(4))) float floatx4;

#define INV_SQRT2F 0.70710678118654752440f

__device__ __forceinline__ ushort f2bf(float f) {
    union { float f; uint32_t u; } c; c.f = f;
    uint32_t x = c.u;
    return (ushort)((x + 0x7fffu + ((x >> 16) & 1u)) >> 16);  // RTNE
}
// softplus(beta=100) = max(x,0) + log(1+exp(-100|x|))/100, native exp/log
__device__ __forceinline__ float softplus100(float x) {
    float z = 100.f * x;
    return fmaxf(x, 0.f) + __logf(1.f + __expf(-fabsf(z))) * 0.01f;
}
// XOR-swizzled column offset (8-elem granules): 2-way max bank aliasing (free)
__device__ __forceinline__ int swz(int row, int col) {
    return (((col >> 3) ^ (row & 7)) << 3) | (col & 7);
}

// ---------------- weight cvt + fragment reorder ----------------
// dest layout per cluster: short8 index i8 = (t*K32 + kc)*64 + lane,
// element j: n = t*16 + (lane&15), k = kc*32 + (lane>>4)*8 + j. Zeros at edges.
struct Seg { const float* s; ushort* d; int nout, kw, k32, ttot, nclust; };
struct CvtAll { Seg seg[16]; };

__global__ void k_cvt(CvtAll c) {
    Seg sg = c.seg[blockIdx.y];
    const int pcs8 = sg.ttot * sg.k32 * 64;   // short8 per cluster
    const int tot8 = pcs8 * sg.nclust;
    for (int i8 = blockIdx.x * blockDim.x + threadIdx.x; i8 < tot8;
         i8 += gridDim.x * blockDim.x) {
        int cl = i8 / pcs8;
        int r = i8 - cl * pcs8;
        int t = r / (sg.k32 * 64);
        int r2 = r - t * (sg.k32 * 64);
        int kc = r2 >> 6;
        int lane = r2 & 63;
        int n = t * 16 + (lane & 15);
        int kb = kc * 32 + (lane >> 4) * 8;
        const float* src = sg.s + (size_t)cl * sg.nout * sg.kw;
        short8 v = {0, 0, 0, 0, 0, 0, 0, 0};
        if (n < sg.nout) {
#pragma unroll
            for (int j = 0; j < 8; ++j) {
                int k = kb + j;
                if (k < sg.kw) v[j] = (short)f2bf(src[n * sg.kw + k]);
            }
        }
        *(short8*)(sg.d + (size_t)i8 * 8) = v;
    }
}

// ---------------- embedding ----------------
template<int STRIDE>
__device__ void embed64(short* act, const float* pts, int row0, short* inp_sv) {
    for (int idx = threadIdx.x; idx < 64 * 64; idx += 512) {
        int row = idx >> 6, col = idx & 63;
        float v = 0.f;
        if (col < 39) {
            int comp = (col < 3) ? col : (col - 3) % 3;
            float x = pts[(row0 + row) * 3 + comp];
            if (col < 3) v = x;
            else {
                int b = col - 3; int fi = b / 6; int r = b % 6;
                float a = x * (float)(1 << fi);
                v = (r < 3) ? __sinf(a) : __cosf(a);
            }
        }
        act[row * STRIDE + swz(row, col)] = (short)f2bf(v);
        if (inp_sv && col < 39) inp_sv[row * 40 + col] = (short)f2bf(v * INV_SQRT2F);
    }
}

// ---------------- fast layer: fragment-ordered bf16 weights ----------------
template<int ACT, int STRIDE, int K>
__device__ void layer_fast(short* act, const ushort* __restrict__ Wf,
                           const float* __restrict__ bias, int Nout, float scale,
                           bool toLds, float* gOut, int gCol0, int gRow0)
{
    constexpr int K32 = K / 32;
    const int tid = threadIdx.x;
    const int wave = tid >> 6, lane = tid & 63;
    const int q = lane >> 4, li = lane & 15;
    const int Ttot = (Nout + 15) >> 4;

    floatx4 acc[4][4];
#pragma unroll
    for (int i = 0; i < 4; ++i)
#pragma unroll
        for (int m = 0; m < 4; ++m) acc[i][m] = (floatx4){0.f, 0.f, 0.f, 0.f};

    bool tv[4]; int nn[4]; const ushort* wb[4];
#pragma unroll
    for (int i = 0; i < 4; ++i) {
        int t = wave + 8 * i;
        tv[i] = t < Ttot;
        nn[i] = t * 16 + li;
        wb[i] = Wf + (size_t)t * K32 * 512 + lane * 8;
    }

    auto loadB = [&](int kc, short8* b) {
#pragma unroll
        for (int i = 0; i < 4; ++i) {
            short8 z = {0, 0, 0, 0, 0, 0, 0, 0};
            b[i] = tv[i] ? *(const short8*)(wb[i] + kc * 512) : z;
        }
    };
    auto step = [&](int kc, short8* b) {
        short8 afr[4];
        const int gq = kc * 4 + q;
#pragma unroll
        for (int m = 0; m < 4; ++m) {
            int row = m * 16 + li;
            afr[m] = *(const short8*)&act[row * STRIDE + ((gq ^ (row & 7)) << 3)];
        }
#pragma unroll
        for (int i = 0; i < 4; ++i) {
            if (!tv[i]) continue;
#pragma unroll
            for (int m = 0; m < 4; ++m)
                acc[i][m] = __builtin_amdgcn_mfma_f32_16x16x32_bf16(afr[m], b[i], acc[i][m], 0, 0, 0);
        }
    };

    short8 b0[4], b1[4];
    loadB(0, b0);
#pragma unroll
    for (int kc = 0; kc < K32; kc += 2) {
        if (kc + 1 < K32) loadB(kc + 1, b1);
        step(kc, b0);
        if (kc + 2 < K32) loadB(kc + 2, b0);
        if (kc + 1 < K32) step(kc + 1, b1);
    }
    __syncthreads();  // act reads done before epilogue overwrites
#pragma unroll
    for (int i = 0; i < 4; ++i) {
        if (!tv[i]) continue;
        int n = nn[i];
        if (n < Nout) {
            float bs = bias[n];
#pragma unroll
            for (int m = 0; m < 4; ++m) {
                int rbase = m * 16 + q * 4;
#pragma unroll
                for (int r = 0; r < 4; ++r) {
                    float v = acc[i][m][r] + bs;
                    if (ACT == 1) v = softplus100(v);
                    else if (ACT == 2) v = fmaxf(v, 0.f);
                    else if (ACT == 3) v = tanhf(v);
                    v *= scale;
                    if (toLds) act[(rbase + r) * STRIDE + swz(rbase + r, n)] = (short)f2bf(v);
                    else gOut[(size_t)(gRow0 + rbase + r) * 263 + gCol0 + n] = v;
                }
            }
        }
    }
}

// ---------------- fused kernel (fast path) ----------------
struct FAll {
    const ushort* iW[9]; const float* ib[9];
    const ushort* dW[4]; const float* db[4];
    const ushort* mW[3]; const float* mb[3];
};

__global__ __launch_bounds__(512, 4) void k_fused(const float* __restrict__ pts,
                                                  FAll p, float* __restrict__ out,
                                                  int nbI, int nbD, int rpc) {
    __shared__ short act[64 * 512];
    __shared__ short inp_sv[64 * 40];
    const int bid = blockIdx.x;
    if (bid < nbI) {
        const int row0 = bid * 64;
        embed64<512>(act, pts, row0, inp_sv);
        __syncthreads();
        layer_fast<1, 512, 64>(act, p.iW[0], p.ib[0], 512, 1.f, true, nullptr, 0, 0);
        __syncthreads();
        layer_fast<1, 512, 512>(act, p.iW[1], p.ib[1], 512, 1.f, true, nullptr, 0, 0);
        __syncthreads();
        layer_fast<1, 512, 512>(act, p.iW[2], p.ib[2], 512, 1.f, true, nullptr, 0, 0);
        __syncthreads();
        // layer 3: softplus, then pre-scale by 1/sqrt(2) (skip-concat scale)
        layer_fast<1, 512, 512>(act, p.iW[3], p.ib[3], 473, INV_SQRT2F, true, nullptr, 0, 0);
        for (int idx = threadIdx.x; idx < 64 * 64; idx += 512) {
            int row = idx >> 6, col = idx & 63;
            if (col < 39) act[row * 512 + swz(row, 473 + col)] = inp_sv[row * 40 + col];
        }
        __syncthreads();
        layer_fast<1, 512, 512>(act, p.iW[4], p.ib[4], 512, 1.f, true, nullptr, 0, 0);
        __syncthreads();
        layer_fast<1, 512, 512>(act, p.iW[5], p.ib[5], 512, 1.f, true, nullptr, 0, 0);
        __syncthreads();
        layer_fast<1, 512, 512>(act, p.iW[6], p.ib[6], 512, 1.f, true, nullptr, 0, 0);
        __syncthreads();
        layer_fast<1, 512, 512>(act, p.iW[7], p.ib[7], 512, 1.f, true, nullptr, 0, 0);
        __syncthreads();
        layer_fast<0, 512, 512>(act, p.iW[8], p.ib[8], 257, 1.f, false, out, 0, row0);
    } else if (bid < nbI + nbD) {
        const int row0 = (bid - nbI) * 64;
        embed64<512>(act, pts, row0, nullptr);
        __syncthreads();
        layer_fast<2, 512, 64>(act, p.dW[0], p.db[0], 512, 1.f, true, nullptr, 0, 0);
        __syncthreads();
        layer_fast<2, 512, 512>(act, p.dW[1], p.db[1], 512, 1.f, true, nullptr, 0, 0);
        __syncthreads();
        layer_fast<2, 512, 512>(act, p.dW[2], p.db[2], 512, 1.f, true, nullptr, 0, 0);
        __syncthreads();
        layer_fast<3, 512, 512>(act, p.dW[3], p.db[3], 3, 1.f, false, out, 257, row0);
    } else {
        const int row0 = (bid - nbI - nbD) * 64;
        const int c = row0 / rpc;
        // per-cluster fragment sizes: L0 8*2*512, L1 8*4*512, L2 1*4*512
        const ushort* w0 = p.mW[0] + (size_t)c * 8192;
        const ushort* w1 = p.mW[1] + (size_t)c * 16384;
        const ushort* w2 = p.mW[2] + (size_t)c * 2048;
        embed64<128>(act, pts, row0, nullptr);
        __syncthreads();
        layer_fast<2, 128, 64>(act, w0, p.mb[0] + c * 128, 128, 1.f, true, nullptr, 0, 0);
        __syncthreads();
        layer_fast<2, 128, 128>(act, w1, p.mb[1] + c * 128, 128, 1.f, true, nullptr, 0, 0);
        __syncthreads();
        layer_fast<3, 128, 128>(act, w2, p.mb[2] + c * 3, 3, 1.f, false, out, 260, row0);
    }
}

// ---------------- fallback path (fp32 weights read directly) ----------------
template<int ACT, int STRIDE>
__device__ void layer_slow(short* act, const float* Wv, const float* bias,
                           int K, int Kw, int Nout, float scale,
                           bool toLds, float* gOut, int gCol0, int gRow0)
{
    const int tid = threadIdx.x;
    const int wave = tid >> 6, lane = tid & 63;
    const int q = lane >> 4, li = lane & 15;
    const int Ttot = (Nout + 15) >> 4;

    floatx4 acc[4][4];
#pragma unroll
    for (int i = 0; i < 4; ++i)
#pragma unroll
        for (int m = 0; m < 4; ++m) acc[i][m] = (floatx4){0.f, 0.f, 0.f, 0.f};

    bool tv[4]; int nn[4];
#pragma unroll
    for (int i = 0; i < 4; ++i) {
        int t = wave + 8 * i;
        tv[i] = t < Ttot;
        nn[i] = t * 16 + li;
    }
    for (int k0 = 0; k0 < K; k0 += 32) {
        short8 bfr[4];
#pragma unroll
        for (int i = 0; i < 4; ++i) {
            short8 z = {0, 0, 0, 0, 0, 0, 0, 0};
            bfr[i] = z;
            if (tv[i]) {
                int n = nn[i];
#pragma unroll
                for (int j = 0; j < 8; ++j) {
                    int k = k0 + q * 8 + j;
                    if (n < Nout && k < Kw) bfr[i][j] = (short)f2bf(Wv[n * Kw + k]);
                }
            }
        }
        short8 afr[4];
        const int gq = (k0 >> 3) + q;
#pragma unroll
        for (int m = 0; m < 4; ++m) {
            int row = m * 16 + li;
            afr[m] = *(const short8*)&act[row * STRIDE + ((gq ^ (row & 7)) << 3)];
        }
#pragma unroll
        for (int i = 0; i < 4; ++i) {
            if (!tv[i]) continue;
#pragma unroll
            for (int m = 0; m < 4; ++m)
                acc[i][m] = __builtin_amdgcn_mfma_f32_16x16x32_bf16(afr[m], bfr[i], acc[i][m], 0, 0, 0);
        }
    }
    __syncthreads();
#pragma unroll
    for (int i = 0; i < 4; ++i) {
        if (!tv[i]) continue;
        int n = nn[i];
        if (n < Nout) {
            float bs = bias[n];
#pragma unroll
            for (int m = 0; m < 4; ++m) {
                int rbase = m * 16 + q * 4;
#pragma unroll
                for (int r = 0; r < 4; ++r) {
                    float v = acc[i][m][r] + bs;
                    if (ACT == 1) v = softplus100(v);
                    else if (ACT == 2) v = fmaxf(v, 0.f);
                    else if (ACT == 3) v = tanhf(v);
                    v *= scale;
                    if (toLds) act[(rbase + r) * STRIDE + swz(rbase + r, n)] = (short)f2bf(v);
                    else gOut[(size_t)(gRow0 + rbase + r) * 263 + gCol0 + n] = v;
                }
            }
        }
    }
}

struct SAll {
    const float* iW[9]; const float* ib[9];
    const float* dW[4]; const float* db[4];
    const float* mW[3]; const float* mb[3];
};

__global__ __launch_bounds__(512, 4) void k_slow(const float* __restrict__ pts,
                                                 SAll p, float* __restrict__ out,
                                                 int nbI, int nbD, int rpc) {
    __shared__ short act[64 * 512];
    __shared__ short inp_sv[64 * 40];
    const int bid = blockIdx.x;
    if (bid < nbI) {
        const int row0 = bid * 64;
        embed64<512>(act, pts, row0, inp_sv);
        __syncthreads();
        layer_slow<1, 512>(act, p.iW[0], p.ib[0], 64, 39, 512, 1.f, true, nullptr, 0, 0);
        __syncthreads();
        layer_slow<1, 512>(act, p.iW[1], p.ib[1], 512, 512, 512, 1.f, true, nullptr, 0, 0);
        __syncthreads();
        layer_slow<1, 512>(act, p.iW[2], p.ib[2], 512, 512, 512, 1.f, true, nullptr, 0, 0);
        __syncthreads();
        layer_slow<1, 512>(act, p.iW[3], p.ib[3], 512, 512, 473, INV_SQRT2F, true, nullptr, 0, 0);
        for (int idx = threadIdx.x; idx < 64 * 64; idx += 512) {
            int row = idx >> 6, col = idx & 63;
            if (col < 39) act[row * 512 + swz(row, 473 + col)] = inp_sv[row * 40 + col];
        }
        __syncthreads();
        layer_slow<1, 512>(act, p.iW[4], p.ib[4], 512, 512, 512, 1.f, true, nullptr, 0, 0);
        __syncthreads();
        layer_slow<1, 512>(act, p.iW[5], p.ib[5], 512, 512, 512, 1.f, true, nullptr, 0, 0);
        __syncthreads();
        layer_slow<1, 512>(act, p.iW[6], p.ib[6], 512, 512, 512, 1.f, true, nullptr, 0, 0);
        __syncthreads();
        layer_slow<1, 512>(act, p.iW[7], p.ib[7], 512, 512, 512, 1.f, true, nullptr, 0, 0);
        __syncthreads();
        layer_slow<0, 512>(act, p.iW[8], p.ib[8], 512, 512, 257, 1.f, false, out, 0, row0);
    } else if (bid < nbI + nbD) {
        const int row0 = (bid - nbI) * 64;
        embed64<512>(act, pts, row0, nullptr);
        __syncthreads();
        layer_slow<2, 512>(act, p.dW[0], p.db[0], 64, 39, 512, 1.f, true, nullptr, 0, 0);
        __syncthreads();
        layer_slow<2, 512>(act, p.dW[1], p.db[1], 512, 512, 512, 1.f, true, nullptr, 0, 0);
        __syncthreads();
        layer_slow<2, 512>(act, p.dW[2], p.db[2], 512, 512, 512, 1.f, true, nullptr, 0, 0);
        __syncthreads();
        layer_slow<3, 512>(act, p.dW[3], p.db[3], 512, 512, 3, 1.f, false, out, 257, row0);
    } else {
        const int row0 = (bid - nbI - nbD) * 64;
        const int c = row0 / rpc;
        embed64<128>(act, pts, row0, nullptr);
        __syncthreads();
        layer_slow<2, 128>(act, p.mW[0] + c * 128 * 39, p.mb[0] + c * 128, 64, 39, 128, 1.f, true, nullptr, 0, 0);
        __syncthreads();
        layer_slow<2, 128>(act, p.mW[1] + c * 128 * 128, p.mb[1] + c * 128, 128, 128, 128, 1.f, true, nullptr, 0, 0);
        __syncthreads();
        layer_slow<3, 128>(act, p.mW[2] + c * 3 * 128, p.mb[2] + c * 3, 128, 128, 3, 1.f, false, out, 260, row0);
    }
}

extern "C" void kernel_launch(void* const* d_in, const int* in_sizes, int n_in,
                              void* d_out, int out_size, void* d_ws, size_t ws_size,
                              hipStream_t stream) {
    const float* pts = (const float*)d_in[0];
    float* out = (float*)d_out;
    const int N = in_sizes[0] / 3;       // 32768
    const int nbI = N / 64;              // 512
    const int nbD = N / 64;              // 512
    const int nbM = N / 64;              // 512
    const int rpc = N / 64;              // rows per cluster (512)

    // layer geometry: {Nout, Kw, Kpad}
    const int iN[9] = {512, 512, 512, 473, 512, 512, 512, 512, 257};
    const int iK[9] = {39, 512, 512, 512, 512, 512, 512, 512, 512};
    const int dN[4] = {512, 512, 512, 3};
    const int dK[4] = {39, 512, 512, 512};
    const int mN[3] = {128, 128, 3};
    const int mK[3] = {39, 128, 128};

    CvtAll cv; FAll fp; SAll sp;
    size_t off = 0; int seg = 0;
    ushort* wsp = (ushort*)d_ws;
    auto add_seg = [&](const float* src, int nout, int kw, int nclust,
                       const ushort** dstp) {
        int kpad = (kw + 31) & ~31;
        int k32 = kpad / 32;
        int ttot = (nout + 15) >> 4;
        cv.seg[seg].s = src; cv.seg[seg].d = wsp + off;
        cv.seg[seg].nout = nout; cv.seg[seg].kw = kw;
        cv.seg[seg].k32 = k32; cv.seg[seg].ttot = ttot; cv.seg[seg].nclust = nclust;
        *dstp = wsp + off;
        off += (size_t)ttot * k32 * 512 * nclust;
        ++seg;
    };
    for (int l = 0; l < 9; ++l) {
        add_seg((const float*)d_in[1 + 2 * l], iN[l], iK[l], 1, &fp.iW[l]);
        fp.ib[l] = (const float*)d_in[2 + 2 * l];
        sp.iW[l] = (const float*)d_in[1 + 2 * l]; sp.ib[l] = fp.ib[l];
    }
    for (int l = 0; l < 4; ++l) {
        add_seg((const float*)d_in[19 + 2 * l], dN[l], dK[l], 1, &fp.dW[l]);
        fp.db[l] = (const float*)d_in[20 + 2 * l];
        sp.dW[l] = (const float*)d_in[19 + 2 * l]; sp.db[l] = fp.db[l];
    }
    for (int l = 0; l < 3; ++l) {
        add_seg((const float*)d_in[27 + 2 * l], mN[l], mK[l], 64, &fp.mW[l]);
        fp.mb[l] = (const float*)d_in[28 + 2 * l];
        sp.mW[l] = (const float*)d_in[27 + 2 * l]; sp.mb[l] = fp.mb[l];
    }
    const bool use_ws = ws_size >= off * sizeof(ushort);
    const int nb = nbI + nbD + nbM;

    if (use_ws) {
        k_cvt<<<dim3(128, 16), 256, 0, stream>>>(cv);
        k_fused<<<nb, 512, 0, stream>>>(pts, fp, out, nbI, nbD, rpc);
    } else {
        k_slow<<<nb, 512, 0, stream>>>(pts, sp, out, nbI, nbD, rpc);
    }
}

// Round 5
// 458.953 us; speedup vs baseline: 1.6834x; 1.6834x over previous
//
#include <hip/hip_runtime.h>
#include <stdint.h>

typedef __attribute__((ext_vector_type(8))) short short8;
typedef __attribute__((ext_vector_type(4))) float floatx4;

#define INV_SQRT2F 0.70710678118654752440f

// fragment-ordered bf16 weights live here (8.5 MB), filled by k_cvt each call
__device__ ushort g_wbuf[4259840];

__device__ __forceinline__ ushort f2bf(float f) {
    union { float f; uint32_t u; } c; c.f = f;
    uint32_t x = c.u;
    return (ushort)((x + 0x7fffu + ((x >> 16) & 1u)) >> 16);  // RTNE
}
// softplus(beta=100) = max(x,0) + log(1+exp(-100|x|))/100, native exp/log
__device__ __forceinline__ float softplus100(float x) {
    float z = 100.f * x;
    return fmaxf(x, 0.f) + __logf(1.f + __expf(-fabsf(z))) * 0.01f;
}
// XOR-swizzled column offset (8-elem granules): 2-way max bank aliasing (free)
__device__ __forceinline__ int swz(int row, int col) {
    return (((col >> 3) ^ (row & 7)) << 3) | (col & 7);
}

// ---------------- weight cvt + fragment reorder ----------------
// dest layout per cluster: short8 index i8 = (t*K32 + kc)*64 + lane,
// element j: n = t*16 + (lane&15), k = kc*32 + (lane>>4)*8 + j. Zeros at edges.
struct Seg { const float* s; int off, nout, kw, k32, ttot, nclust; };
struct CvtAll { Seg seg[16]; };

__global__ void k_cvt(CvtAll c) {
    Seg sg = c.seg[blockIdx.y];
    ushort* d = g_wbuf + sg.off;
    const int pcs8 = sg.ttot * sg.k32 * 64;   // short8 per cluster
    const int tot8 = pcs8 * sg.nclust;
    for (int i8 = blockIdx.x * blockDim.x + threadIdx.x; i8 < tot8;
         i8 += gridDim.x * blockDim.x) {
        int cl = i8 / pcs8;
        int r = i8 - cl * pcs8;
        int t = r / (sg.k32 * 64);
        int r2 = r - t * (sg.k32 * 64);
        int kc = r2 >> 6;
        int lane = r2 & 63;
        int n = t * 16 + (lane & 15);
        int kb = kc * 32 + (lane >> 4) * 8;
        const float* src = sg.s + (size_t)cl * sg.nout * sg.kw;
        short8 v = {0, 0, 0, 0, 0, 0, 0, 0};
        if (n < sg.nout) {
#pragma unroll
            for (int j = 0; j < 8; ++j) {
                int k = kb + j;
                if (k < sg.kw) v[j] = (short)f2bf(src[n * sg.kw + k]);
            }
        }
        *(short8*)(d + (size_t)i8 * 8) = v;
    }
}

// ---------------- embedding: 128 rows, cols 0..63 (zeros beyond 38) ----------------
template<int STRIDE>
__device__ void embed128(short* act, const float* pts, int row0, short* inp_sv) {
    for (int idx = threadIdx.x; idx < 128 * 64; idx += 1024) {
        int row = idx >> 6, col = idx & 63;
        float v = 0.f;
        if (col < 39) {
            int comp = (col < 3) ? col : (col - 3) % 3;
            float x = pts[(row0 + row) * 3 + comp];
            if (col < 3) v = x;
            else {
                int b = col - 3; int fi = b / 6; int r = b % 6;
                float a = x * (float)(1 << fi);
                v = (r < 3) ? __sinf(a) : __cosf(a);
            }
        }
        act[row * STRIDE + swz(row, col)] = (short)f2bf(v);
        if (inp_sv && col < 39) inp_sv[row * 40 + col] = (short)f2bf(v * INV_SQRT2F);
    }
}

// ---------------- one linear layer: 128 rows in LDS, 16 waves ----------------
// wave handles t-tiles {wave, wave+16} x 8 m-tiles; acc = 2x8 floatx4 (64 AGPR)
template<int ACT, int STRIDE, int K>
__device__ void layer_mm(short* act, const ushort* __restrict__ Wf,
                         const float* __restrict__ bias, int Nout, float scale,
                         bool toLds, float* gOut, int gCol0, int gRow0)
{
    constexpr int K32 = K / 32;
    const int tid = threadIdx.x;
    const int wave = tid >> 6, lane = tid & 63;
    const int q = lane >> 4, li = lane & 15;
    const int Ttot = (Nout + 15) >> 4;

    floatx4 acc[2][8];
#pragma unroll
    for (int i = 0; i < 2; ++i)
#pragma unroll
        for (int m = 0; m < 8; ++m) acc[i][m] = (floatx4){0.f, 0.f, 0.f, 0.f};

    bool tv[2]; int nn[2]; const ushort* wb[2];
#pragma unroll
    for (int i = 0; i < 2; ++i) {
        int t = wave + 16 * i;
        tv[i] = t < Ttot;
        nn[i] = t * 16 + li;
        wb[i] = Wf + (size_t)t * K32 * 512 + lane * 8;
    }

    auto loadB = [&](int kc, short8* b) {
#pragma unroll
        for (int i = 0; i < 2; ++i) {
            short8 z = {0, 0, 0, 0, 0, 0, 0, 0};
            b[i] = tv[i] ? *(const short8*)(wb[i] + kc * 512) : z;
        }
    };
    auto step = [&](int kc, short8* b) {
        const int gq = kc * 4 + q;
#pragma unroll
        for (int h = 0; h < 2; ++h) {           // split m into halves: caps VGPR liveness
            short8 afr[4];
#pragma unroll
            for (int m2 = 0; m2 < 4; ++m2) {
                int row = (h * 4 + m2) * 16 + li;
                afr[m2] = *(const short8*)&act[row * STRIDE + ((gq ^ (row & 7)) << 3)];
            }
#pragma unroll
            for (int i = 0; i < 2; ++i) {
                if (!tv[i]) continue;
#pragma unroll
                for (int m2 = 0; m2 < 4; ++m2)
                    acc[i][h * 4 + m2] = __builtin_amdgcn_mfma_f32_16x16x32_bf16(
                        afr[m2], b[i], acc[i][h * 4 + m2], 0, 0, 0);
            }
        }
    };

    short8 b0[2], b1[2];
    loadB(0, b0);
#pragma unroll
    for (int kc = 0; kc < K32; kc += 2) {
        if (kc + 1 < K32) loadB(kc + 1, b1);
        step(kc, b0);
        if (kc + 2 < K32) loadB(kc + 2, b0);
        if (kc + 1 < K32) step(kc + 1, b1);
    }
    __syncthreads();  // act reads done before epilogue overwrites
#pragma unroll
    for (int i = 0; i < 2; ++i) {
        if (!tv[i]) continue;
        int n = nn[i];
        if (n < Nout) {
            float bs = bias[n];
#pragma unroll
            for (int m = 0; m < 8; ++m) {
                int rbase = m * 16 + q * 4;
#pragma unroll
                for (int r = 0; r < 4; ++r) {
                    float v = acc[i][m][r] + bs;
                    if (ACT == 1) v = softplus100(v);
                    else if (ACT == 2) v = fmaxf(v, 0.f);
                    else if (ACT == 3) v = tanhf(v);
                    v *= scale;
                    if (toLds) act[(rbase + r) * STRIDE + swz(rbase + r, n)] = (short)f2bf(v);
                    else gOut[(size_t)(gRow0 + rbase + r) * 263 + gCol0 + n] = v;
                }
            }
        }
    }
}

// ---------------- implicit network: 256 blocks x 1024 (one generation) ----------------
struct IP { int iw[9]; const float* ib[9]; };

__global__ __launch_bounds__(1024, 4) void k_impl(const float* __restrict__ pts,
                                                  IP p, float* __restrict__ out) {
    __shared__ short act[128 * 512];
    __shared__ short inp_sv[128 * 40];
    const int row0 = blockIdx.x * 128;
    embed128<512>(act, pts, row0, inp_sv);
    __syncthreads();
    layer_mm<1, 512, 64>(act, g_wbuf + p.iw[0], p.ib[0], 512, 1.f, true, nullptr, 0, 0);
    __syncthreads();
    layer_mm<1, 512, 512>(act, g_wbuf + p.iw[1], p.ib[1], 512, 1.f, true, nullptr, 0, 0);
    __syncthreads();
    layer_mm<1, 512, 512>(act, g_wbuf + p.iw[2], p.ib[2], 512, 1.f, true, nullptr, 0, 0);
    __syncthreads();
    // layer 3: softplus, then pre-scale by 1/sqrt(2) (skip-concat scale)
    layer_mm<1, 512, 512>(act, g_wbuf + p.iw[3], p.ib[3], 473, INV_SQRT2F, true, nullptr, 0, 0);
    for (int idx = threadIdx.x; idx < 128 * 64; idx += 1024) {
        int row = idx >> 6, col = idx & 63;
        if (col < 39) act[row * 512 + swz(row, 473 + col)] = inp_sv[row * 40 + col];
    }
    __syncthreads();
    layer_mm<1, 512, 512>(act, g_wbuf + p.iw[4], p.ib[4], 512, 1.f, true, nullptr, 0, 0);
    __syncthreads();
    layer_mm<1, 512, 512>(act, g_wbuf + p.iw[5], p.ib[5], 512, 1.f, true, nullptr, 0, 0);
    __syncthreads();
    layer_mm<1, 512, 512>(act, g_wbuf + p.iw[6], p.ib[6], 512, 1.f, true, nullptr, 0, 0);
    __syncthreads();
    layer_mm<1, 512, 512>(act, g_wbuf + p.iw[7], p.ib[7], 512, 1.f, true, nullptr, 0, 0);
    __syncthreads();
    layer_mm<0, 512, 512>(act, g_wbuf + p.iw[8], p.ib[8], 257, 1.f, false, out, 0, row0);
}

// ---------------- displacement + multi networks (small, share L2 fine) ----------------
struct DMP { int dw[4]; const float* db[4]; int mw[3]; const float* mb[3]; };

__global__ __launch_bounds__(1024, 4) void k_dm(const float* __restrict__ pts,
                                                DMP p, float* __restrict__ out,
                                                int nbD, int rpc) {
    __shared__ short act[128 * 512];
    const int bid = blockIdx.x;
    if (bid < nbD) {
        const int row0 = bid * 128;
        embed128<512>(act, pts, row0, nullptr);
        __syncthreads();
        layer_mm<2, 512, 64>(act, g_wbuf + p.dw[0], p.db[0], 512, 1.f, true, nullptr, 0, 0);
        __syncthreads();
        layer_mm<2, 512, 512>(act, g_wbuf + p.dw[1], p.db[1], 512, 1.f, true, nullptr, 0, 0);
        __syncthreads();
        layer_mm<2, 512, 512>(act, g_wbuf + p.dw[2], p.db[2], 512, 1.f, true, nullptr, 0, 0);
        __syncthreads();
        layer_mm<3, 512, 512>(act, g_wbuf + p.dw[3], p.db[3], 3, 1.f, false, out, 257, row0);
    } else {
        const int row0 = (bid - nbD) * 128;
        const int c = row0 / rpc;
        // per-cluster fragment sizes: L0 8*2*512=8192, L1 8*4*512=16384, L2 1*4*512=2048
        const ushort* w0 = g_wbuf + p.mw[0] + c * 8192;
        const ushort* w1 = g_wbuf + p.mw[1] + c * 16384;
        const ushort* w2 = g_wbuf + p.mw[2] + c * 2048;
        embed128<128>(act, pts, row0, nullptr);
        __syncthreads();
        layer_mm<2, 128, 64>(act, w0, p.mb[0] + c * 128, 128, 1.f, true, nullptr, 0, 0);
        __syncthreads();
        layer_mm<2, 128, 128>(act, w1, p.mb[1] + c * 128, 128, 1.f, true, nullptr, 0, 0);
        __syncthreads();
        layer_mm<3, 128, 128>(act, w2, p.mb[2] + c * 3, 3, 1.f, false, out, 260, row0);
    }
}

extern "C" void kernel_launch(void* const* d_in, const int* in_sizes, int n_in,
                              void* d_out, int out_size, void* d_ws, size_t ws_size,
                              hipStream_t stream) {
    const float* pts = (const float*)d_in[0];
    float* out = (float*)d_out;
    const int N = in_sizes[0] / 3;       // 32768
    const int nbI = N / 128;             // 256
    const int nbD = N / 128;             // 256
    const int nbM = N / 128;             // 256
    const int rpc = N / 64;              // rows per cluster (512)

    const int iN[9] = {512, 512, 512, 473, 512, 512, 512, 512, 257};
    const int iK[9] = {39, 512, 512, 512, 512, 512, 512, 512, 512};
    const int dN[4] = {512, 512, 512, 3};
    const int dK[4] = {39, 512, 512, 512};
    const int mN[3] = {128, 128, 3};
    const int mK[3] = {39, 128, 128};

    CvtAll cv; IP ip; DMP dm;
    int off = 0, seg = 0;
    auto add_seg = [&](const float* src, int nout, int kw, int nclust) -> int {
        int k32 = ((kw + 31) & ~31) / 32;
        int ttot = (nout + 15) >> 4;
        cv.seg[seg].s = src; cv.seg[seg].off = off;
        cv.seg[seg].nout = nout; cv.seg[seg].kw = kw;
        cv.seg[seg].k32 = k32; cv.seg[seg].ttot = ttot; cv.seg[seg].nclust = nclust;
        int my = off;
        off += ttot * k32 * 512 * nclust;
        ++seg;
        return my;
    };
    for (int l = 0; l < 9; ++l) {
        ip.iw[l] = add_seg((const float*)d_in[1 + 2 * l], iN[l], iK[l], 1);
        ip.ib[l] = (const float*)d_in[2 + 2 * l];
    }
    for (int l = 0; l < 4; ++l) {
        dm.dw[l] = add_seg((const float*)d_in[19 + 2 * l], dN[l], dK[l], 1);
        dm.db[l] = (const float*)d_in[20 + 2 * l];
    }
    for (int l = 0; l < 3; ++l) {
        dm.mw[l] = add_seg((const float*)d_in[27 + 2 * l], mN[l], mK[l], 64);
        dm.mb[l] = (const float*)d_in[28 + 2 * l];
    }
    // off == 4259840 == sizeof(g_wbuf)/2 by construction

    k_cvt<<<dim3(256, 16), 256, 0, stream>>>(cv);
    k_impl<<<nbI, 1024, 0, stream>>>(pts, ip, out);
    k_dm<<<nbD + nbM, 1024, 0, stream>>>(pts, dm, out, nbD, rpc);
}